// Round 1
// baseline (409.790 us; speedup 1.0000x reference)
//
#include <hip/hip_runtime.h>

// Problem constants (fixed by setup_inputs)
#define NB 8      // batch
#define CC 8      // channels
#define TT 600    // time frames
#define FF 513    // freq bins
#define NCHUNK 40 // t-chunks for covariance partials
#define TC 15     // TT / NCHUNK
#define LOADC 7.0710678118654755e-4f  // 0.001/sqrt(2)

// ---------------------------------------------------------------------------
// Kernel A: one pass over target; per-thread (n, chunk, f) partial stats:
//   s[t]   = sum_c x[c,t] * conj(d[c])
//   nume[c]+= x[c,t] * conj(s[t])        (16 floats)
//   dd     += |s[t]|^2                   (1 float)
// Partials layout: part[((n*NCHUNK+chunk)*17 + k)*FF + f]  (coalesced over f)
// ---------------------------------------------------------------------------
__global__ __launch_bounds__(256) void cov_partial_kernel(
    const float* __restrict__ x, const float* __restrict__ sv,
    float* __restrict__ part)
{
    int idx = blockIdx.x * blockDim.x + threadIdx.x;
    const int total = NB * NCHUNK * FF;
    if (idx >= total) return;
    int f = idx % FF;
    int rest = idx / FF;
    int chunk = rest % NCHUNK;
    int n = rest / NCHUNK;

    // steering vector d[f,c] = sv[0,f,c] + i*sv[1,f,c]   (layout [2,F,C,1])
    float dr[CC], di[CC];
#pragma unroll
    for (int c = 0; c < CC; ++c) {
        dr[c] = sv[f * CC + c];
        di[c] = sv[FF * CC + f * CC + c];
    }

    const long planeT = (long)TT * FF;  // one (ri,c) plane
    const float* xb = x + (long)n * 2 * CC * planeT + (long)(chunk * TC) * FF + f;

    float nr[CC], ni[CC];
#pragma unroll
    for (int c = 0; c < CC; ++c) { nr[c] = 0.f; ni[c] = 0.f; }
    float dd = 0.f;

    for (int t = 0; t < TC; ++t) {
        long toff = (long)t * FF;
        float xr[CC], xi[CC];
#pragma unroll
        for (int c = 0; c < CC; ++c) {
            xr[c] = xb[(long)c * planeT + toff];            // real part (ri=0)
            xi[c] = xb[(long)(CC + c) * planeT + toff];     // imag part (ri=1)
        }
        // s = sum_c x[c] * conj(d[c])
        float sr = 0.f, si = 0.f;
#pragma unroll
        for (int c = 0; c < CC; ++c) {
            sr += xr[c] * dr[c] + xi[c] * di[c];
            si += xi[c] * dr[c] - xr[c] * di[c];
        }
        // nume[c] += x[c] * conj(s);  dd += |s|^2
#pragma unroll
        for (int c = 0; c < CC; ++c) {
            nr[c] += xr[c] * sr + xi[c] * si;
            ni[c] += xi[c] * sr - xr[c] * si;
        }
        dd += sr * sr + si * si;
    }

    float* pb = part + ((long)(n * NCHUNK + chunk) * 17) * FF + f;
#pragma unroll
    for (int c = 0; c < CC; ++c) {
        pb[(long)(2 * c) * FF]     = nr[c];
        pb[(long)(2 * c + 1) * FF] = ni[c];
    }
    pb[(long)16 * FF] = dd;
}

// ---------------------------------------------------------------------------
// Kernel B: reduce chunks, apply diagonal loading, w = nume/deno.
// w layout: w[((n*CC + c)*2 + ri)*FF + f]   (coalesced over f)
// ---------------------------------------------------------------------------
__global__ __launch_bounds__(256) void finalize_w_kernel(
    const float* __restrict__ part, const float* __restrict__ sv,
    float* __restrict__ w)
{
    int idx = blockIdx.x * blockDim.x + threadIdx.x;
    const int total = NB * FF;
    if (idx >= total) return;
    int f = idx % FF;
    int n = idx / FF;

    float nr[CC], ni[CC];
#pragma unroll
    for (int c = 0; c < CC; ++c) { nr[c] = 0.f; ni[c] = 0.f; }
    float dd = 0.f;

    for (int chunk = 0; chunk < NCHUNK; ++chunk) {
        const float* pb = part + ((long)(n * NCHUNK + chunk) * 17) * FF + f;
#pragma unroll
        for (int c = 0; c < CC; ++c) {
            nr[c] += pb[(long)(2 * c) * FF];
            ni[c] += pb[(long)(2 * c + 1) * FF];
        }
        dd += pb[(long)16 * FF];
    }

    float dr[CC], di[CC];
    float S = 0.f;
#pragma unroll
    for (int c = 0; c < CC; ++c) {
        dr[c] = sv[f * CC + c];
        di[c] = sv[FF * CC + f * CC + c];
        S += dr[c] * dr[c] + di[c] * di[c];
    }

    const float invT = 1.0f / (float)TT;
    // deno = dd/T + LOAD*(1+i)*S
    float den_r = dd * invT + LOADC * S;
    float den_i = LOADC * S;
    float inv_mag = 1.0f / (den_r * den_r + den_i * den_i);

#pragma unroll
    for (int c = 0; c < CC; ++c) {
        // nume[c] = acc/T + LOAD*(1+i)*d[c]
        float numr = nr[c] * invT + LOADC * (dr[c] - di[c]);
        float numi = ni[c] * invT + LOADC * (dr[c] + di[c]);
        // w = nume * conj(deno) / |deno|^2
        float wr = (numr * den_r + numi * den_i) * inv_mag;
        float wi = (numi * den_r - numr * den_i) * inv_mag;
        w[((long)(n * CC + c) * 2 + 0) * FF + f] = wr;
        w[((long)(n * CC + c) * 2 + 1) * FF + f] = wi;
    }
}

// ---------------------------------------------------------------------------
// Kernel C: beamform mixture:  xbf[n,f,t] = sum_c conj(w[n,f,c]) y[n,c,t,f]
// Output layout [N,2,1,T,F]: out[((n*2+ri)*TT + t)*FF + f]
// ---------------------------------------------------------------------------
__global__ __launch_bounds__(256) void beamform_kernel(
    const float* __restrict__ y, const float* __restrict__ w,
    float* __restrict__ out)
{
    int idx = blockIdx.x * blockDim.x + threadIdx.x;
    const int total = NB * TT * FF;
    if (idx >= total) return;
    int f = idx % FF;
    int t = (idx / FF) % TT;
    int n = idx / (TT * FF);

    const long planeT = (long)TT * FF;
    const float* yb = y + (long)n * 2 * CC * planeT + (long)t * FF + f;

    float or_ = 0.f, oi = 0.f;
#pragma unroll
    for (int c = 0; c < CC; ++c) {
        float yr = yb[(long)c * planeT];
        float yi = yb[(long)(CC + c) * planeT];
        float wr = w[((long)(n * CC + c) * 2 + 0) * FF + f];
        float wi = w[((long)(n * CC + c) * 2 + 1) * FF + f];
        // conj(w)*y = (wr - i wi)(yr + i yi)
        or_ += wr * yr + wi * yi;
        oi  += wr * yi - wi * yr;
    }
    out[((long)(n * 2 + 0) * TT + t) * FF + f] = or_;
    out[((long)(n * 2 + 1) * TT + t) * FF + f] = oi;
}

// ---------------------------------------------------------------------------
extern "C" void kernel_launch(void* const* d_in, const int* in_sizes, int n_in,
                              void* d_out, int out_size, void* d_ws, size_t ws_size,
                              hipStream_t stream) {
    const float* mixture  = (const float*)d_in[0];
    // d_in[1] = noise: unused by the reference
    const float* target   = (const float*)d_in[2];
    const float* steering = (const float*)d_in[3];
    float* out = (float*)d_out;

    float* part = (float*)d_ws;                                  // NB*NCHUNK*17*FF floats
    float* w    = part + (long)NB * NCHUNK * 17 * FF;            // NB*CC*2*FF floats

    {
        int total = NB * NCHUNK * FF;
        int blocks = (total + 255) / 256;
        cov_partial_kernel<<<blocks, 256, 0, stream>>>(target, steering, part);
    }
    {
        int total = NB * FF;
        int blocks = (total + 255) / 256;
        finalize_w_kernel<<<blocks, 256, 0, stream>>>(part, steering, w);
    }
    {
        int total = NB * TT * FF;
        int blocks = (total + 255) / 256;
        beamform_kernel<<<blocks, 256, 0, stream>>>(mixture, w, out);
    }
}